// Round 12
// baseline (155.212 us; speedup 1.0000x reference)
//
#include <hip/hip_runtime.h>
#include <hip/hip_cooperative_groups.h>
#include <hip/hip_fp16.h>
#include <math.h>

namespace cg = cooperative_groups;

// GSchNet continuous-filter convolution edge embedding.
// out[e,:] = f(dist(e)) where f: R -> R^128 (RBF+MLP) is a smooth function of
// ONE scalar. Tabulate f on [0,16] (f16 rows), lerp per edge.
//
// Ledger: R2/R5 baseline 114.1. R3/R4 multi-row A BANNED. R6 NT PERMANENT.
// R7 TABK=1024 -> 105.9. R8 pipeline NEUTRAL (latency hidden). R9 f16 table
// -3 (not read-BW-bound). R10 fuse B into C -19.4 (83.6). R11 lane-parallel t
// NEUTRAL (84.9) -> C is write-fabric-bound ~12% above mixed-stream floor.
// R12 = fuse A into C via cooperative launch: grid-stride row build (R2-shaped
// per-128-thread rows, NOT the banned variant), grid.sync(), R11's C core
// grid-strided. Saves launch gap + A tail; A's W traffic halves (paired rows
// share cache lines). Fallback to R11 two-kernel path if coop launch errors.

#define N_NODES_C   50000
#define N_EDGES_C   800000
#define LATENT_C    128
#define N_CENTERS_C 100
#define TABK        1024
#define DMAX        16.0f
#define LN2F        0.69314718056f
#define NWAVEUNITS  (N_EDGES_C / 64)   // 12500

typedef float  v4f __attribute__((ext_vector_type(4)));
typedef _Float16 h4 __attribute__((ext_vector_type(4)));

__device__ __forceinline__ float shifted_softplus(float x) {
    return fmaxf(x, 0.0f) + log1pf(expf(-fabsf(x))) - LN2F;
}

// ---- shared device body: build one table row (128 threads, row index `row`)
__device__ __forceinline__ void build_row(const float* __restrict__ W1,
                                          const float* __restrict__ b1,
                                          const float* __restrict__ W2,
                                          const float* __restrict__ b2,
                                          _Float16* __restrict__ table,
                                          float* rbf, float* hbuf,
                                          int j, int row, bool active) {
    const float d = (float)row * (DMAX / (float)TABK);
    if (j < N_CENTERS_C) {
        const float c = (float)j * (10.0f / 99.0f);   // linspace(0,10,100)
        const float x = d - c;
        rbf[j] = expf(-x * x);
    }
    __syncthreads();

    float a = b1[j];
    #pragma unroll 4
    for (int c = 0; c < N_CENTERS_C; ++c)
        a = fmaf(rbf[c], W1[c * LATENT_C + j], a);
    hbuf[j] = shifted_softplus(a);
    __syncthreads();

    float o = b2[j];
    #pragma unroll 4
    for (int i = 0; i < LATENT_C; ++i)
        o = fmaf(hbuf[i], W2[i * LATENT_C + j], o);

    if (active) table[(size_t)row * LATENT_C + j] = (_Float16)o;
    __syncthreads();   // protect rbf/hbuf before next grid-stride row
}

// -------- Fused cooperative kernel: A (grid-stride rows) -> grid.sync -> C.
__global__ void fused_kernel(const float* __restrict__ nodes,
                             const int* __restrict__ senders,
                             const int* __restrict__ receivers,
                             const float* __restrict__ W1, const float* __restrict__ b1,
                             const float* __restrict__ W2, const float* __restrict__ b2,
                             _Float16* __restrict__ table,
                             float* __restrict__ out) {
    // ---- Phase A: 2 rows per block-iteration (one per 128-thread half)
    {
        __shared__ float rbf[2][N_CENTERS_C];
        __shared__ float hbuf[2][LATENT_C];
        const int sub = threadIdx.x >> 7;
        const int j   = threadIdx.x & 127;
        for (int r0 = blockIdx.x * 2; r0 <= TABK; r0 += gridDim.x * 2) {
            const int row = r0 + sub;
            build_row(W1, b1, W2, b2, table, rbf[sub], hbuf[sub], j, row, row <= TABK);
        }
    }
    cg::this_grid().sync();

    // ---- Phase C (R11 core, grid-strided): wave owns 64 edges/unit.
    const int lane = threadIdx.x & 63;
    const int half = lane >> 5;          // edge within a store slot
    const int li   = lane & 31;          // half4 index within the 128-h row
    const int wid  = (blockIdx.x * blockDim.x + threadIdx.x) >> 6;
    const int nw   = (gridDim.x * blockDim.x) >> 6;

    for (int w = wid; w < NWAVEUNITS; w += nw) {
        const int base = w * 64;

        // scalar phase: one edge per lane
        const int e = base + lane;
        const int s = senders[e];
        const int r = receivers[e];
        const float dx = nodes[3 * s + 0] - nodes[3 * r + 0];
        const float dy = nodes[3 * s + 1] - nodes[3 * r + 1];
        const float dz = nodes[3 * s + 2] - nodes[3 * r + 2];
        const float dist = sqrtf(fmaf(dx, dx, fmaf(dy, dy, dz * dz)));
        const float t = fminf(dist * ((float)TABK / DMAX), (float)TABK - 0.5f);

        // write phase: 4 edges per sub-iter
        #pragma unroll 4
        for (int i = 0; i < 16; ++i) {
            const int eb = base + 4 * i;
            const float t0 = __shfl(t, 4 * i + half, 64);
            const float t1 = __shfl(t, 4 * i + 2 + half, 64);
            const int   k0 = (int)t0;  const float f0 = t0 - (float)k0;
            const int   k1 = (int)t1;  const float f1 = t1 - (float)k1;

            const h4* p0 = (const h4*)(table + (size_t)k0 * LATENT_C);
            const h4* p1 = (const h4*)(table + (size_t)k1 * LATENT_C);
            const h4 a0 = p0[li], b0 = p0[li + 32];   // +32 h4 = next row
            const h4 a1 = p1[li], b1 = p1[li + 32];

            v4f o0, o1;
            #pragma unroll
            for (int c = 0; c < 4; ++c) {
                const float A0 = (float)a0[c], B0 = (float)b0[c];
                const float A1 = (float)a1[c], B1 = (float)b1[c];
                o0[c] = fmaf(f0, B0 - A0, A0);
                o1[c] = fmaf(f1, B1 - A1, A1);
            }

            v4f* po0 = (v4f*)(out + (size_t)eb * LATENT_C);
            v4f* po1 = (v4f*)(out + (size_t)(eb + 2) * LATENT_C);
            __builtin_nontemporal_store(o0, &po0[lane]);
            __builtin_nontemporal_store(o1, &po1[lane]);
        }
    }
}

// -------- R11 two-kernel fallback path (if cooperative launch unavailable)
__global__ void build_table_kernel(const float* __restrict__ W1, const float* __restrict__ b1,
                                   const float* __restrict__ W2, const float* __restrict__ b2,
                                   _Float16* __restrict__ table) {
    __shared__ float rbf[N_CENTERS_C];
    __shared__ float hbuf[LATENT_C];
    build_row(W1, b1, W2, b2, table, rbf, hbuf, threadIdx.x, blockIdx.x, true);
}

__global__ void edge_write_kernel(const float* __restrict__ nodes,
                                  const int* __restrict__ senders,
                                  const int* __restrict__ receivers,
                                  const _Float16* __restrict__ table,
                                  float* __restrict__ out) {
    const int lane = threadIdx.x & 63;
    const int half = lane >> 5;
    const int li   = lane & 31;
    const int wid  = (blockIdx.x * blockDim.x + threadIdx.x) >> 6;
    const int base = wid * 64;

    const int e = base + lane;
    const int s = senders[e];
    const int r = receivers[e];
    const float dx = nodes[3 * s + 0] - nodes[3 * r + 0];
    const float dy = nodes[3 * s + 1] - nodes[3 * r + 1];
    const float dz = nodes[3 * s + 2] - nodes[3 * r + 2];
    const float dist = sqrtf(fmaf(dx, dx, fmaf(dy, dy, dz * dz)));
    const float t = fminf(dist * ((float)TABK / DMAX), (float)TABK - 0.5f);

    #pragma unroll 4
    for (int i = 0; i < 16; ++i) {
        const int eb = base + 4 * i;
        const float t0 = __shfl(t, 4 * i + half, 64);
        const float t1 = __shfl(t, 4 * i + 2 + half, 64);
        const int   k0 = (int)t0;  const float f0 = t0 - (float)k0;
        const int   k1 = (int)t1;  const float f1 = t1 - (float)k1;

        const h4* p0 = (const h4*)(table + (size_t)k0 * LATENT_C);
        const h4* p1 = (const h4*)(table + (size_t)k1 * LATENT_C);
        const h4 a0 = p0[li], b0 = p0[li + 32];
        const h4 a1 = p1[li], b1 = p1[li + 32];

        v4f o0, o1;
        #pragma unroll
        for (int c = 0; c < 4; ++c) {
            const float A0 = (float)a0[c], B0 = (float)b0[c];
            const float A1 = (float)a1[c], B1 = (float)b1[c];
            o0[c] = fmaf(f0, B0 - A0, A0);
            o1[c] = fmaf(f1, B1 - A1, A1);
        }

        v4f* po0 = (v4f*)(out + (size_t)eb * LATENT_C);
        v4f* po1 = (v4f*)(out + (size_t)(eb + 2) * LATENT_C);
        __builtin_nontemporal_store(o0, &po0[lane]);
        __builtin_nontemporal_store(o1, &po1[lane]);
    }
}

// -------- Fallback (ws too small): direct per-edge MLP
__global__ void edge_direct_kernel(const float* __restrict__ nodes,
                                   const int* __restrict__ senders,
                                   const int* __restrict__ receivers,
                                   const float* __restrict__ W1, const float* __restrict__ b1,
                                   const float* __restrict__ W2, const float* __restrict__ b2,
                                   float* __restrict__ out) {
    __shared__ float rbf[N_CENTERS_C];
    __shared__ float hbuf[LATENT_C];
    const int j = threadIdx.x;

    for (int e = blockIdx.x; e < N_EDGES_C; e += gridDim.x) {
        const int s = senders[e];
        const int r = receivers[e];
        const float dx = nodes[3 * s + 0] - nodes[3 * r + 0];
        const float dy = nodes[3 * s + 1] - nodes[3 * r + 1];
        const float dz = nodes[3 * s + 2] - nodes[3 * r + 2];
        const float dist = sqrtf(fmaf(dx, dx, fmaf(dy, dy, dz * dz)));

        if (j < N_CENTERS_C) {
            const float c = (float)j * (10.0f / 99.0f);
            const float x = dist - c;
            rbf[j] = expf(-x * x);
        }
        __syncthreads();

        float a = b1[j];
        #pragma unroll 4
        for (int c = 0; c < N_CENTERS_C; ++c)
            a = fmaf(rbf[c], W1[c * LATENT_C + j], a);
        hbuf[j] = shifted_softplus(a);
        __syncthreads();

        float o = b2[j];
        #pragma unroll 4
        for (int i = 0; i < LATENT_C; ++i)
            o = fmaf(hbuf[i], W2[i * LATENT_C + j], o);
        out[(size_t)e * LATENT_C + j] = o;

        __syncthreads();
    }
}

extern "C" void kernel_launch(void* const* d_in, const int* in_sizes, int n_in,
                              void* d_out, int out_size, void* d_ws, size_t ws_size,
                              hipStream_t stream) {
    const float* nodes     = (const float*)d_in[0];
    const int*   senders   = (const int*)  d_in[1];
    const int*   receivers = (const int*)  d_in[2];
    const float* W1        = (const float*)d_in[3];
    const float* b1        = (const float*)d_in[4];
    const float* W2        = (const float*)d_in[5];
    const float* b2        = (const float*)d_in[6];
    float*       out       = (float*)d_out;

    const size_t table_bytes = (size_t)(TABK + 1) * LATENT_C * sizeof(_Float16); // 262,400

    if (ws_size < table_bytes) {
        edge_direct_kernel<<<16384, LATENT_C, 0, stream>>>(nodes, senders, receivers,
                                                           W1, b1, W2, b2, out);
        return;
    }

    _Float16* table = (_Float16*)d_ws;

    // Co-residency-safe grid for the cooperative launch.
    int blocksPerCU = 0;
    hipError_t oerr = hipOccupancyMaxActiveBlocksPerMultiprocessor(
        &blocksPerCU, fused_kernel, 256, 0);
    int grid = 1024;                           // conservative default (4/CU)
    if (oerr == hipSuccess && blocksPerCU >= 1) {
        grid = blocksPerCU * 256;
        if (grid > 2048) grid = 2048;          // 2048 x 4 waves = residency cap
    }

    void* args[] = {(void*)&nodes, (void*)&senders, (void*)&receivers,
                    (void*)&W1, (void*)&b1, (void*)&W2, (void*)&b2,
                    (void*)&table, (void*)&out};
    hipError_t lerr = hipLaunchCooperativeKernel((const void*)fused_kernel,
                                                 dim3(grid), dim3(256),
                                                 args, 0, stream);
    if (lerr != hipSuccess) {
        // Fallback: R11 two-kernel path.
        build_table_kernel<<<TABK + 1, LATENT_C, 0, stream>>>(W1, b1, W2, b2, table);
        edge_write_kernel<<<NWAVEUNITS / 4, 256, 0, stream>>>(nodes, senders, receivers,
                                                              table, out);
    }
}

// Round 13
// 83.191 us; speedup vs baseline: 1.8657x; 1.8657x over previous
//
#include <hip/hip_runtime.h>
#include <hip/hip_fp16.h>
#include <math.h>

// GSchNet continuous-filter convolution edge embedding.
// out[e,:] = f(dist(e)) where f: R -> R^128 (RBF+MLP) is a smooth function of
// ONE scalar. Tabulate f on [0,16] (f16 rows), lerp per edge.
//
// Ledger: R2/R5 baseline 114.1. R3/R4 multi-row A BANNED (real regression,
// mechanism unknown). R6 NT PERMANENT. R7 TABK=1024 -> 105.9. R8 SW-pipeline
// NEUTRAL (latency TLP-hidden). R9 f16 table -3 (not read-BW-bound).
// R10 fuse B into C -> 83.6 BEST. R11 lane-parallel t NEUTRAL (not
// issue-bound). R12 cooperative A+C fusion -> 155 REGRESSION, BANNED
// (occupancy-capped grid strangles write parallelism).
// R13 = R10 source exactly, ONE change: TABK 1024 -> 512. A's W re-read
// traffic halves (~4 -> ~2us). Lerp err ~2e-3 + f16 ~1e-3 stays under the
// 1.5e-2 threshold with >=2.5x margin. If neutral: R10 is the roofline.

#define N_NODES_C   50000
#define N_EDGES_C   800000
#define LATENT_C    128
#define N_CENTERS_C 100
#define TABK        512
#define DMAX        16.0f
#define LN2F        0.69314718056f

typedef float  v4f __attribute__((ext_vector_type(4)));
typedef _Float16 h4 __attribute__((ext_vector_type(4)));

__device__ __forceinline__ float shifted_softplus(float x) {
    return fmaxf(x, 0.0f) + log1pf(expf(-fabsf(x))) - LN2F;
}

// -------- Phase A: one block (128 threads) per table row k, d = k*(DMAX/TABK)
// Stores f16 rows (256 B/row).
__global__ void build_table_kernel(const float* __restrict__ W1, const float* __restrict__ b1,
                                   const float* __restrict__ W2, const float* __restrict__ b2,
                                   _Float16* __restrict__ table) {
    __shared__ float rbf[N_CENTERS_C];
    __shared__ float hbuf[LATENT_C];
    const int j = threadIdx.x;
    const float d = (float)blockIdx.x * (DMAX / (float)TABK);

    if (j < N_CENTERS_C) {
        const float c = (float)j * (10.0f / 99.0f);   // linspace(0,10,100)
        const float x = d - c;
        rbf[j] = expf(-x * x);
    }
    __syncthreads();

    float a = b1[j];
    #pragma unroll 4
    for (int c = 0; c < N_CENTERS_C; ++c)
        a = fmaf(rbf[c], W1[c * LATENT_C + j], a);
    hbuf[j] = shifted_softplus(a);
    __syncthreads();

    float o = b2[j];
    #pragma unroll 4
    for (int i = 0; i < LATENT_C; ++i)
        o = fmaf(hbuf[i], W2[i * LATENT_C + j], o);

    table[(size_t)blockIdx.x * LATENT_C + j] = (_Float16)o;
}

// -------- Phase C (fused with B): half-wave (32 lanes) per edge; 2 slots =
// 4 edges/iter. Each lane of a half-wave redundantly loads its edge's indices
// and endpoint coords (same-address -> L2 broadcast), computes dist -> t
// inline, then f16-row lerp in f32 + NT float4 stores. [identical to R10]
__global__ void edge_write_kernel(const float* __restrict__ nodes,
                                  const int* __restrict__ senders,
                                  const int* __restrict__ receivers,
                                  const _Float16* __restrict__ table,
                                  float* __restrict__ out) {
    const int lane = threadIdx.x & 63;
    const int half = lane >> 5;          // edge within a slot
    const int li   = lane & 31;          // half4 index within the 128-h row
    const int wid  = (blockIdx.x * blockDim.x + threadIdx.x) >> 6;
    const int nw   = (gridDim.x * blockDim.x) >> 6;

    for (int base = wid * 4; base + 3 < N_EDGES_C; base += nw * 4) {
        // slot 0: edges base, base+1 ; slot 1: edges base+2, base+3
        const int e0 = base + half;
        const int e1 = base + 2 + half;

        const int s0 = senders[e0],  r0i = receivers[e0];
        const int s1 = senders[e1],  r1i = receivers[e1];

        const float dx0 = nodes[3 * s0 + 0] - nodes[3 * r0i + 0];
        const float dy0 = nodes[3 * s0 + 1] - nodes[3 * r0i + 1];
        const float dz0 = nodes[3 * s0 + 2] - nodes[3 * r0i + 2];
        const float dx1 = nodes[3 * s1 + 0] - nodes[3 * r1i + 0];
        const float dy1 = nodes[3 * s1 + 1] - nodes[3 * r1i + 1];
        const float dz1 = nodes[3 * s1 + 2] - nodes[3 * r1i + 2];

        const float dist0 = sqrtf(fmaf(dx0, dx0, fmaf(dy0, dy0, dz0 * dz0)));
        const float dist1 = sqrtf(fmaf(dx1, dx1, fmaf(dy1, dy1, dz1 * dz1)));

        // clamp so k+1 <= TABK stays in table
        const float t0 = fminf(dist0 * ((float)TABK / DMAX), (float)TABK - 0.5f);
        const float t1 = fminf(dist1 * ((float)TABK / DMAX), (float)TABK - 0.5f);
        const int   k0 = (int)t0;  const float f0 = t0 - (float)k0;
        const int   k1 = (int)t1;  const float f1 = t1 - (float)k1;

        const h4* p0 = (const h4*)(table + (size_t)k0 * LATENT_C);
        const h4* p1 = (const h4*)(table + (size_t)k1 * LATENT_C);
        const h4 a0 = p0[li], b0 = p0[li + 32];   // +32 h4 = next row (k0+1)
        const h4 a1 = p1[li], b1 = p1[li + 32];

        v4f o0, o1;
        #pragma unroll
        for (int c = 0; c < 4; ++c) {
            const float A0 = (float)a0[c], B0 = (float)b0[c];
            const float A1 = (float)a1[c], B1 = (float)b1[c];
            o0[c] = fmaf(f0, B0 - A0, A0);
            o1[c] = fmaf(f1, B1 - A1, A1);
        }

        v4f* po0 = (v4f*)(out + (size_t)base * LATENT_C);        // edges base,base+1
        v4f* po1 = (v4f*)(out + (size_t)(base + 2) * LATENT_C);  // edges base+2,base+3
        __builtin_nontemporal_store(o0, &po0[lane]);
        __builtin_nontemporal_store(o1, &po1[lane]);
    }
}

// -------- Fallback (ws too small): direct per-edge MLP
__global__ void edge_direct_kernel(const float* __restrict__ nodes,
                                   const int* __restrict__ senders,
                                   const int* __restrict__ receivers,
                                   const float* __restrict__ W1, const float* __restrict__ b1,
                                   const float* __restrict__ W2, const float* __restrict__ b2,
                                   float* __restrict__ out) {
    __shared__ float rbf[N_CENTERS_C];
    __shared__ float hbuf[LATENT_C];
    const int j = threadIdx.x;

    for (int e = blockIdx.x; e < N_EDGES_C; e += gridDim.x) {
        const int s = senders[e];
        const int r = receivers[e];
        const float dx = nodes[3 * s + 0] - nodes[3 * r + 0];
        const float dy = nodes[3 * s + 1] - nodes[3 * r + 1];
        const float dz = nodes[3 * s + 2] - nodes[3 * r + 2];
        const float dist = sqrtf(fmaf(dx, dx, fmaf(dy, dy, dz * dz)));

        if (j < N_CENTERS_C) {
            const float c = (float)j * (10.0f / 99.0f);
            const float x = dist - c;
            rbf[j] = expf(-x * x);
        }
        __syncthreads();

        float a = b1[j];
        #pragma unroll 4
        for (int c = 0; c < N_CENTERS_C; ++c)
            a = fmaf(rbf[c], W1[c * LATENT_C + j], a);
        hbuf[j] = shifted_softplus(a);
        __syncthreads();

        float o = b2[j];
        #pragma unroll 4
        for (int i = 0; i < LATENT_C; ++i)
            o = fmaf(hbuf[i], W2[i * LATENT_C + j], o);
        out[(size_t)e * LATENT_C + j] = o;

        __syncthreads();
    }
}

extern "C" void kernel_launch(void* const* d_in, const int* in_sizes, int n_in,
                              void* d_out, int out_size, void* d_ws, size_t ws_size,
                              hipStream_t stream) {
    const float* nodes     = (const float*)d_in[0];
    const int*   senders   = (const int*)  d_in[1];
    const int*   receivers = (const int*)  d_in[2];
    const float* W1        = (const float*)d_in[3];
    const float* b1        = (const float*)d_in[4];
    const float* W2        = (const float*)d_in[5];
    const float* b2        = (const float*)d_in[6];
    float*       out       = (float*)d_out;

    const size_t table_bytes = (size_t)(TABK + 1) * LATENT_C * sizeof(_Float16); // 131,328

    if (ws_size >= table_bytes) {
        _Float16* table = (_Float16*)d_ws;

        build_table_kernel<<<TABK + 1, LATENT_C, 0, stream>>>(W1, b1, W2, b2, table);
        // 2048 blocks x 4 waves = 8192 waves = exactly the 256CU x 32wave residency cap
        edge_write_kernel<<<2048, 256, 0, stream>>>(nodes, senders, receivers, table, out);
    } else {
        edge_direct_kernel<<<16384, LATENT_C, 0, stream>>>(nodes, senders, receivers,
                                                           W1, b1, W2, b2, out);
    }
}